// Round 2
// baseline (406.414 us; speedup 1.0000x reference)
//
#include <hip/hip_runtime.h>
#include <hip/hip_bf16.h>

// Problem constants (fixed by the harness / reference setup_inputs)
#define B_ 2
#define K_ 33
#define N_ 50000
#define E_ 800000
#define R_ 200
#define D_ 64
#define L_ 3

#define NBW 3125          // dual-bit bitset dwords (fallback path only)
#define ROWCAP 96872      // rowlist entry capacity
#define NV4 200000        // E/4 int4-groups
#define SCAT_BLOCKS 391   // fallback scan grid
#define SCAT_THREADS (SCAT_BLOCKS * 256)
#define SCANBLK 196       // ceil(N/256) blocks for degree scan

// flags[row] bits: 1 = x-active, 2 = touched this layer, 4 = rowlist claim.

__device__ inline float wave_sum64(float v) {
    for (int m = 32; m; m >>= 1) v += __shfl_xor(v, m, 64);
    return v;
}

// Decode `batch` (int64 [B,K,3] or int32 — detect via hi-words all zero) and
// seed x[b,h0,:] = query[b] = rel[b,r0,:]; claim h0 rows. One block, 128 thr.
__global__ void init_kernel(const int* __restrict__ raw,
                            int* __restrict__ hb, int* __restrict__ rb,
                            int* __restrict__ tb,
                            float* __restrict__ x, int* __restrict__ flags,
                            unsigned* __restrict__ bitset,   // scratch in CSR path
                            int* __restrict__ rowlist, int* __restrict__ rowcnt,
                            int* __restrict__ frontcnt,
                            const float* __restrict__ rel) {
    __shared__ int stride_s;
    __shared__ int hs[B_], rs[B_];
    if (threadIdx.x == 0) {
        int all_hi_zero = 1;
        for (int i = 0; i < 99; i++)
            if (raw[2 * i + 1] != 0) { all_hi_zero = 0; break; }
        stride_s = all_hi_zero ? 2 : 1;
        *frontcnt = B_;
    }
    __syncthreads();
    int st = stride_s;
    for (int i = threadIdx.x; i < B_ * K_; i += blockDim.x)
        tb[i] = raw[(i * 3 + 1) * st];          // t_index[b,k]
    if (threadIdx.x < B_) {
        int b = threadIdx.x;
        int h = raw[(b * K_ * 3 + 0) * st];     // h_index[b,0]
        int r = raw[(b * K_ * 3 + 2) * st];     // r_index[b,0]
        hb[b] = h; rb[b] = r; hs[b] = h; rs[b] = r;
    }
    __syncthreads();
    int b = threadIdx.x >> 6;                   // 0..1
    int lane = threadIdx.x & 63;
    int node = hs[b];
    int row = b * N_ + node;
    x[row * D_ + lane] = rel[(b * R_ + rs[b]) * D_ + lane];
    if (lane == 0) {
        atomicOr(&flags[row], 1 | 4);
        atomicOr(&bitset[node >> 4], 1u << (((node & 15) << 1) | b));
        int idx = atomicAdd(rowcnt, 1);
        if (idx < ROWCAP) rowlist[idx] = row;
    }
}

// ---------------- CSR build (once per launch) ----------------

__global__ void hist_kernel(const int* __restrict__ ei, int* __restrict__ deg) {
    const int4* s4 = (const int4*)ei;
    int stride = gridDim.x * blockDim.x;
    for (int i = blockIdx.x * blockDim.x + threadIdx.x; i < NV4; i += stride) {
        int4 u = s4[i];
        atomicAdd(&deg[u.x], 1); atomicAdd(&deg[u.y], 1);
        atomicAdd(&deg[u.z], 1); atomicAdd(&deg[u.w], 1);
    }
}

// Block-local exclusive scan of 256 degree bins; emit block totals.
__global__ void deg_scan_a(const int* __restrict__ deg, int* __restrict__ rowptr,
                           int* __restrict__ blockSum) {
    __shared__ int s[256];
    int b = blockIdx.x, t = threadIdx.x, i = b * 256 + t;
    int v = (i < N_) ? deg[i] : 0;
    s[t] = v;
    __syncthreads();
    for (int off = 1; off < 256; off <<= 1) {
        int u = (t >= off) ? s[t - off] : 0;
        __syncthreads();
        s[t] += u;
        __syncthreads();
    }
    if (i < N_) rowptr[i] = s[t] - v;           // exclusive within block
    if (t == 255) blockSum[b] = s[255];
}

// Add cross-block offsets; materialize rowptr and the placement cursor.
__global__ void deg_scan_b(int* __restrict__ rowptr, const int* __restrict__ blockSum,
                           int* __restrict__ cursor) {
    __shared__ int s[256];
    int b = blockIdx.x, t = threadIdx.x;
    s[t] = (t < b) ? blockSum[t] : 0;           // b <= 195 < 256
    __syncthreads();
    for (int off = 128; off; off >>= 1) {
        if (t < off) s[t] += s[t + off];
        __syncthreads();
    }
    int offv = s[0];
    int i = b * 256 + t;
    if (i < N_) {
        int v = rowptr[i] + offv;
        rowptr[i] = v;
        cursor[i] = v;
    }
    if (b == 0 && t == 0) rowptr[N_] = E_;
}

// Scatter each edge into its src's CSR slot, packed dst | (type<<16).
// dst < 50000 < 2^16, type < 200 < 2^16 — lossless.
__global__ void place_kernel(const int* __restrict__ ei, const int* __restrict__ etype,
                             int* __restrict__ cursor, unsigned* __restrict__ ecsr) {
    const int4* s4 = (const int4*)ei;
    const int4* d4 = (const int4*)(ei + E_);    // E_*4 bytes is 16B-aligned
    const int4* t4 = (const int4*)etype;
    int stride = gridDim.x * blockDim.x;
    for (int i = blockIdx.x * blockDim.x + threadIdx.x; i < NV4; i += stride) {
        int4 s = s4[i]; int4 d = d4[i]; int4 t = t4[i];
        int p;
        p = atomicAdd(&cursor[s.x], 1); ecsr[p] = (unsigned)d.x | ((unsigned)t.x << 16);
        p = atomicAdd(&cursor[s.y], 1); ecsr[p] = (unsigned)d.y | ((unsigned)t.y << 16);
        p = atomicAdd(&cursor[s.z], 1); ecsr[p] = (unsigned)d.z | ((unsigned)t.z << 16);
        p = atomicAdd(&cursor[s.w], 1); ecsr[p] = (unsigned)d.w | ((unsigned)t.w << 16);
    }
}

// ---------------- Frontier-driven gather (replaces the O(E) scan) ----------------
// One wave per x-active row (frontier = rowlist[0 .. frontcnt), where frontcnt
// was snapshotted by the PREVIOUS update/init — rows claimed during this
// kernel are intentionally excluded (their x is unwritten). Lanes pre-load up
// to 64 edges of the row, broadcast via shfl; atomicAdds are fire-and-forget.
__global__ void gather_kernel(const float* __restrict__ x, float* __restrict__ agg,
                              const unsigned* __restrict__ ecsr,
                              const int* __restrict__ rowptr,
                              const float* __restrict__ rel,
                              int* __restrict__ flags,
                              int* __restrict__ rowlist, int* __restrict__ rowcnt,
                              const int* __restrict__ frontcnt) {
    const int lane = threadIdx.x & 63;
    const int cnt = min(*frontcnt, ROWCAP);
    int idx = blockIdx.x * (blockDim.x >> 6) + (threadIdx.x >> 6);
    const int nw = gridDim.x * (blockDim.x >> 6);
    for (; idx < cnt; idx += nw) {
        int row = rowlist[idx];
        int b = (row >= N_) ? 1 : 0;
        int node = row - b * N_;
        int p0 = rowptr[node];
        int dg = rowptr[node + 1] - p0;
        if (dg <= 0) continue;
        float xv = x[row * D_ + lane];
        for (int base = 0; base < dg; base += 64) {
            int m = min(dg - base, 64);
            unsigned u = (lane < m) ? ecsr[p0 + base + lane] : 0u;
            for (int j = 0; j < m; j++) {
                unsigned uj = __shfl(u, j, 64);
                int di = (int)(uj & 0xFFFFu);
                int ti = (int)(uj >> 16);
                float v = xv * rel[(b * R_ + ti) * D_ + lane];
                atomicAdd(&agg[(b * N_ + di) * D_ + lane], v);
                if (lane == 0) {
                    int old = atomicOr(&flags[b * N_ + di], 2 | 4);
                    if (!(old & 4)) {
                        int k = atomicAdd(rowcnt, 1);
                        if (k < ROWCAP) rowlist[k] = b * N_ + di;
                    }
                }
            }
        }
    }
}

// ---------------- Fallback O(E) scan (round-1 proven path) ----------------
__global__ void scatter_kernel(const float* __restrict__ x, float* __restrict__ agg,
                               const int* __restrict__ ei, const int* __restrict__ etype,
                               const float* __restrict__ rel,
                               int* __restrict__ flags,
                               const unsigned* __restrict__ bitset,
                               int* __restrict__ rowlist, int* __restrict__ rowcnt) {
    __shared__ uint4 bs4[782];
    unsigned* bs = (unsigned*)bs4;
    const uint4* g4 = (const uint4*)bitset;
    for (int i = threadIdx.x; i < 781; i += 256) bs4[i] = g4[i];
    if (threadIdx.x == 0) bs[3124] = bitset[3124];
    const int t = blockIdx.x * 256 + threadIdx.x;
    const int4* s4 = (const int4*)ei;
    int4 u0 = s4[t];
    int v4p1 = t + SCAT_THREADS;
    bool ok1 = v4p1 < NV4;
    int4 u1 = s4[ok1 ? v4p1 : t];
    __syncthreads();
    const int lane = threadIdx.x & 63;
    const int wv4 = blockIdx.x * 256 + (threadIdx.x & ~63);
    #pragma unroll
    for (int p = 0; p < 2; p++) {
        int4 u = p ? u1 : u0;
        bool ok = p ? ok1 : true;
        int sv[4] = {u.x, u.y, u.z, u.w};
        unsigned act = 0;
        if (ok) {
            #pragma unroll
            for (int k = 0; k < 4; k++) {
                int s = sv[k];
                act |= ((bs[s >> 4] >> ((s & 15) << 1)) & 3u) << (k * 2);
            }
        }
        #pragma unroll
        for (int k = 0; k < 4; k++) {
            #pragma unroll
            for (int b = 0; b < B_; b++) {
                unsigned long long mask = __ballot((act >> (k * 2 + b)) & 1);
                while (mask) {
                    int i = __builtin_ctzll(mask);
                    mask &= mask - 1;
                    int e = (wv4 + i + p * SCAT_THREADS) * 4 + k;
                    int si = __shfl(sv[k], i, 64);
                    int di = ei[E_ + e];
                    int ti = etype[e];
                    float v = x[(b * N_ + si) * D_ + lane] * rel[(b * R_ + ti) * D_ + lane];
                    atomicAdd(&agg[(b * N_ + di) * D_ + lane], v);
                    if (lane == 0) {
                        int old = atomicOr(&flags[b * N_ + di], 2 | 4);
                        if (!(old & 4)) {
                            int idx = atomicAdd(rowcnt, 1);
                            if (idx < ROWCAP) rowlist[idx] = b * N_ + di;
                        }
                    }
                }
            }
        }
    }
}

// Fused per-node update over the worklist (unchanged math). Also snapshots
// rowcnt into frontcnt for the next layer's gather, and re-publishes the
// bitset (harmless scratch writes in CSR path).
__global__ void update_kernel(float* __restrict__ x, float* __restrict__ agg,
                              int* __restrict__ flags, unsigned* __restrict__ bitset,
                              const int* __restrict__ rowlist,
                              const int* __restrict__ rowcnt,
                              int* __restrict__ frontcnt,
                              const int* __restrict__ hb, const int* __restrict__ rb,
                              const float* __restrict__ rel,
                              const float* __restrict__ W,    // [128,64] layer l
                              const float* __restrict__ bias, // [64]
                              const float* __restrict__ g,    // [64]
                              const float* __restrict__ be) { // [64]
    const int lane = threadIdx.x & 63;
    const int cnt = min(*rowcnt, ROWCAP);
    if (blockIdx.x == 0 && threadIdx.x == 0) *frontcnt = cnt;  // stable during update
    int idx = blockIdx.x * (blockDim.x >> 6) + (threadIdx.x >> 6);
    const int nw = gridDim.x * (blockDim.x >> 6);
    for (; idx < cnt; idx += nw) {
        int row = rowlist[idx];
        int f = flags[row];
        int b = (row >= N_) ? 1 : 0;
        int node = row - b * N_;
        float a = agg[row * D_ + lane];
        if (row == b * N_ + hb[b])                       // boundary (= query)
            a += rel[(b * R_ + rb[b]) * D_ + lane];
        float xo = (f & 1) ? x[row * D_ + lane] : 0.0f;
        float y = bias[lane];
        #pragma unroll 8
        for (int i = 0; i < 64; i++) {
            float av = __shfl(a, i, 64);
            y += av * W[i * 64 + lane];
        }
        #pragma unroll 8
        for (int i = 0; i < 64; i++) {
            float xv = __shfl(xo, i, 64);
            y += xv * W[(64 + i) * 64 + lane];
        }
        float mu = wave_sum64(y) * (1.0f / 64.0f);
        float dlt = y - mu;
        float var = wave_sum64(dlt * dlt) * (1.0f / 64.0f);
        float upd = dlt * rsqrtf(var + 1e-5f) * g[lane] + be[lane];
        upd = fmaxf(upd, 0.0f);
        x[row * D_ + lane] = upd + xo;
        agg[row * D_ + lane] = 0.0f;            // ready for next layer
        if (lane == 0) {
            flags[row] = (f | 1) & ~2;          // x-active; clear touched
            atomicOr(&bitset[node >> 4], 1u << (((node & 15) << 1) | b));
        }
    }
}

// Final MLP score for the B*K (b,k) pairs. One wave per output.
__global__ void score_kernel(const float* __restrict__ x, const int* __restrict__ flags,
                             const int* __restrict__ tb, const int* __restrict__ rb,
                             const float* __restrict__ rel,
                             const float* __restrict__ w1,  // [128,64]
                             const float* __restrict__ b1,  // [64]
                             const float* __restrict__ w2,  // [64]
                             const float* __restrict__ b2,  // [1]
                             float* __restrict__ out) {
    int idx = blockIdx.x;            // 0 .. B*K-1
    int lane = threadIdx.x;
    int b = idx / K_;
    int t  = tb[idx];
    int r0 = rb[b];
    int row = b * N_ + t;
    float q   = rel[(b * R_ + r0) * D_ + lane];
    float hid = (flags[row] & 1) ? x[row * D_ + lane] : 0.0f;
    float acc = b1[lane];
    #pragma unroll 8
    for (int i = 0; i < 64; i++) acc += __shfl(hid, i, 64) * w1[i * 64 + lane];
    #pragma unroll 8
    for (int i = 0; i < 64; i++) acc += __shfl(q, i, 64) * w1[(64 + i) * 64 + lane];
    acc = fmaxf(acc, 0.0f);
    float s = wave_sum64(acc * w2[lane]);
    if (lane == 0) out[idx] = s + b2[0];
}

extern "C" void kernel_launch(void* const* d_in, const int* in_sizes, int n_in,
                              void* d_out, int out_size, void* d_ws, size_t ws_size,
                              hipStream_t stream) {
    const float* rel     = (const float*)d_in[0];
    const float* layer_w = (const float*)d_in[1];
    const float* layer_b = (const float*)d_in[2];
    const float* ln_g    = (const float*)d_in[3];
    const float* ln_b    = (const float*)d_in[4];
    const float* mlp_w1  = (const float*)d_in[5];
    const float* mlp_b1  = (const float*)d_in[6];
    const float* mlp_w2  = (const float*)d_in[7];
    const float* mlp_b2  = (const float*)d_in[8];
    const int* batch_raw = (const int*)d_in[9];
    const int* ei    = (const int*)d_in[10];
    const int* etype = (const int*)d_in[11];
    (void)in_sizes; (void)n_in; (void)out_size;

    char* ws = (char*)d_ws;

    if (ws_size >= 55801120) {
        // ---------- CSR path ----------
        // x        @ 0           25,600,000  (NOT zeroed; reads gated)
        // agg      @ 25,600,000  25,600,000  (zeroed)
        // flags    @ 51,200,000     400,000  (zeroed)
        // deg      @ 51,600,000     200,000  (zeroed)
        // rowcnt   @ 51,800,000           4  (zeroed)
        // frontcnt @ 51,800,004           4  (zeroed)
        // rowlist  @ 51,800,016     387,488
        // rowptr   @ 52,187,504     200,004  (N+1 entries)
        // blockSum @ 52,387,508         784
        // cursor   @ 52,388,304     200,000
        // ecsr     @ 52,588,304   3,200,000
        // bitsetS  @ 55,788,304      12,512  (scratch: written, never read)
        // hb/rb    @ 55,800,816/824; tb @ 55,800,832 (264) -> end 55,801,096
        float* x        = (float*)(ws);
        float* agg      = (float*)(ws + 25600000);
        int* flags      = (int*)  (ws + 51200000);
        int* deg        = (int*)  (ws + 51600000);
        int* rowcnt     = (int*)  (ws + 51800000);
        int* frontcnt   = (int*)  (ws + 51800004);
        int* rowlist    = (int*)  (ws + 51800016);
        int* rowptr     = (int*)  (ws + 52187504);
        int* blockSum   = (int*)  (ws + 52387508);
        int* cursor     = (int*)  (ws + 52388304);
        unsigned* ecsr  = (unsigned*)(ws + 52588304);
        unsigned* bitsetS = (unsigned*)(ws + 55788304);
        int* hb         = (int*)  (ws + 55800816);
        int* rb         = (int*)  (ws + 55800824);
        int* tb         = (int*)  (ws + 55800832);

        // Zero agg + flags + deg + rowcnt + frontcnt in one memset.
        hipMemsetAsync(ws + 25600000, 0, 26200008, stream);
        init_kernel<<<1, 128, 0, stream>>>(batch_raw, hb, rb, tb, x, flags, bitsetS,
                                           rowlist, rowcnt, frontcnt, rel);
        hist_kernel<<<400, 256, 0, stream>>>(ei, deg);
        deg_scan_a<<<SCANBLK, 256, 0, stream>>>(deg, rowptr, blockSum);
        deg_scan_b<<<SCANBLK, 256, 0, stream>>>(rowptr, blockSum, cursor);
        place_kernel<<<400, 256, 0, stream>>>(ei, etype, cursor, ecsr);

        for (int l = 0; l < L_; l++) {
            gather_kernel<<<256, 256, 0, stream>>>(x, agg, ecsr, rowptr, rel,
                                                   flags, rowlist, rowcnt, frontcnt);
            update_kernel<<<256, 256, 0, stream>>>(x, agg, flags, bitsetS,
                                                   rowlist, rowcnt, frontcnt, hb, rb, rel,
                                                   layer_w + (size_t)l * 128 * 64,
                                                   layer_b + l * 64,
                                                   ln_g + l * 64,
                                                   ln_b + l * 64);
        }
        score_kernel<<<B_ * K_, 64, 0, stream>>>(x, flags, tb, rb, rel, mlp_w1, mlp_b1,
                                                 mlp_w2, mlp_b2, (float*)d_out);
    } else {
        // ---------- Fallback: round-1 proven scan path ----------
        float* x        = (float*)(ws);
        float* agg      = (float*)(ws + 25600000);
        int* flags      = (int*)  (ws + 51200000);
        int* rowlist    = (int*)  (ws + 51600000);
        unsigned* bitset= (unsigned*)(ws + 51987488);
        int* rowcnt     = (int*)  (ws + 52000000);
        int* frontcnt   = (int*)  (ws + 52000004);   // unused gap dword (zeroed)
        int* hb         = (int*)  (ws + 52000008);
        int* rb         = (int*)  (ws + 52000016);
        int* tb         = (int*)  (ws + 52000024);

        hipMemsetAsync(ws + 25600000, 0, 26400288, stream);
        init_kernel<<<1, 128, 0, stream>>>(batch_raw, hb, rb, tb, x, flags, bitset,
                                           rowlist, rowcnt, frontcnt, rel);
        for (int l = 0; l < L_; l++) {
            scatter_kernel<<<SCAT_BLOCKS, 256, 0, stream>>>(x, agg, ei, etype, rel,
                                                            flags, bitset, rowlist, rowcnt);
            update_kernel<<<256, 256, 0, stream>>>(x, agg, flags, bitset,
                                                   rowlist, rowcnt, frontcnt, hb, rb, rel,
                                                   layer_w + (size_t)l * 128 * 64,
                                                   layer_b + l * 64,
                                                   ln_g + l * 64,
                                                   ln_b + l * 64);
        }
        score_kernel<<<B_ * K_, 64, 0, stream>>>(x, flags, tb, rb, rel, mlp_w1, mlp_b1,
                                                 mlp_w2, mlp_b2, (float*)d_out);
    }
}